// Round 6
// baseline (1096.785 us; speedup 1.0000x reference)
//
#include <hip/hip_runtime.h>
#include <hip/hip_bf16.h>
#include <cstddef>

#define BB 8
#define CC 512
#define NN 4096
#define CQ 64
#define MQ 64   // Q-rows per attn block

typedef short bf16x8 __attribute__((ext_vector_type(8)));
typedef short bf16x4 __attribute__((ext_vector_type(4)));
typedef float f32x4  __attribute__((ext_vector_type(4)));

// fp32 -> bf16 bits, round-to-nearest-even
static __device__ __forceinline__ unsigned bf16_bits(float f){
  unsigned u = __float_as_uint(f);
  u += 0x7fffu + ((u >> 16) & 1u);
  return u >> 16;
}
static __device__ __forceinline__ unsigned pack2bf(float lo, float hi){
  return bf16_bits(lo) | (bf16_bits(hi) << 16);
}

// ---- weights fp32 -> bf16 (Wqk packed: rows 0..63 = Wq, 64..127 = Wk) ----
__global__ __launch_bounds__(256) void cvt_w_kernel(
    const float* __restrict__ Wq, const float* __restrict__ Wk,
    const float* __restrict__ Wv,
    short* __restrict__ Wqkbf, short* __restrict__ Wvbf){
  const int i = blockIdx.x*256 + threadIdx.x;
  if (i < CQ*CC){
    Wqkbf[i]         = (short)bf16_bits(Wq[i]);
    Wqkbf[CQ*CC + i] = (short)bf16_bits(Wk[i]);
  }
  Wvbf[i] = (short)bf16_bits(Wv[i]);
}

// ---- x fp32 [b][c][n] -> xT bf16 [b][n][c] via LDS 64x64 tile ----
__global__ __launch_bounds__(256) void cvt_x_kernel(
    const float* __restrict__ x, short* __restrict__ xT){
  __shared__ float lds[64*67];
  const int tid = threadIdx.x;
  const int n0 = blockIdx.x*64, c0 = blockIdx.y*64, b = blockIdx.z;
  const int nl = tid & 63, cw = tid >> 6;
  const float* xp = x + ((size_t)b*CC + c0)*NN + n0;
#pragma unroll
  for (int i=0;i<16;++i){
    const int cl = cw*16 + i;
    lds[nl*67 + cl] = xp[(size_t)cl*NN + nl];
  }
  __syncthreads();
  short* xTp = xT + ((size_t)b*NN + n0)*CC + c0;
#pragma unroll
  for (int p=0;p<2;++p){
    const int nl2 = (tid>>3) + p*32;
    const int c8 = (tid&7)*8;
    const float* r = &lds[nl2*67 + c8];
    uint4 v;
    v.x = pack2bf(r[0], r[1]);
    v.y = pack2bf(r[2], r[3]);
    v.z = pack2bf(r[4], r[5]);
    v.w = pack2bf(r[6], r[7]);
    *(uint4*)&xTp[(size_t)nl2*CC + c8] = v;
  }
}

// ---- Q,K projection via MFMA: D[n][o] = xT . Wqk^T;  Qbf/Kbf layout [b][n][64] ----
__global__ __launch_bounds__(256) void proj_qk_mfma(
    const short* __restrict__ xT, const short* __restrict__ Wqkbf,
    const float* __restrict__ bq, const float* __restrict__ bk,
    short* __restrict__ Qbf, short* __restrict__ Kbf){
  const int tid  = threadIdx.x;
  const int lane = tid & 63;
  const int w    = tid >> 6;
  const int iq   = lane & 15;
  const int q    = lane >> 4;
  const int b    = blockIdx.z;
  const int n0w  = blockIdx.x*128 + w*32;

  f32x4 acc[2][8];
#pragma unroll
  for (int ns=0;ns<2;++ns)
#pragma unroll
    for (int os=0;os<8;++os) acc[ns][os] = (f32x4){0.f,0.f,0.f,0.f};

  const short* Abase = xT + ((size_t)b*NN + n0w + iq)*CC + q*8;
  const short* Bbase = Wqkbf + (size_t)iq*CC + q*8;

  for (int ks=0; ks<16; ++ks){
    const int k = ks*32;
    bf16x8 af[2], bf[8];
#pragma unroll
    for (int ns=0;ns<2;++ns) af[ns] = *(const bf16x8*)(Abase + (size_t)ns*16*CC + k);
#pragma unroll
    for (int os=0;os<8;++os) bf[os] = *(const bf16x8*)(Bbase + (size_t)os*16*CC + k);
#pragma unroll
    for (int ns=0;ns<2;++ns)
#pragma unroll
      for (int os=0;os<8;++os)
        acc[ns][os] = __builtin_amdgcn_mfma_f32_16x16x32_bf16(af[ns], bf[os], acc[ns][os], 0,0,0);
  }
#pragma unroll
  for (int ns=0;ns<2;++ns){
#pragma unroll
    for (int os=0;os<8;++os){
      const int o = (os&4) ? ((os-4)*16 + iq) : (os*16 + iq);
      const float bias = (os<4) ? bq[o] : bk[o];
      short* dst = (os<4) ? Qbf : Kbf;
#pragma unroll
      for (int r=0;r<4;++r){
        const int n = n0w + ns*16 + q*4 + r;
        dst[((size_t)b*NN + n)*CQ + o] = (short)bf16_bits(acc[ns][os][r] + bias);
      }
    }
  }
}

// ---- V projection via MFMA: D[c][n] = Wv . x;  Vbf layout [b][c][n] ----
__global__ __launch_bounds__(256) void proj_v_mfma(
    const short* __restrict__ xT, const short* __restrict__ Wvbf,
    const float* __restrict__ bv, short* __restrict__ Vbf){
  const int tid  = threadIdx.x;
  const int lane = tid & 63;
  const int w    = tid >> 6;
  const int iq   = lane & 15;
  const int q    = lane >> 4;
  const int b    = blockIdx.z;
  const int c0w  = blockIdx.y*128 + (w&1)*64;
  const int n0w  = blockIdx.x*64 + (w>>1)*32;

  f32x4 acc[4][2];
#pragma unroll
  for (int cs=0;cs<4;++cs)
#pragma unroll
    for (int ns=0;ns<2;++ns) acc[cs][ns] = (f32x4){0.f,0.f,0.f,0.f};

  const short* Abase = Wvbf + (size_t)(c0w + iq)*CC + q*8;
  const short* Bbase = xT + ((size_t)b*NN + n0w + iq)*CC + q*8;

  for (int ks=0; ks<16; ++ks){
    const int k = ks*32;
    bf16x8 af[4], bf[2];
#pragma unroll
    for (int cs=0;cs<4;++cs) af[cs] = *(const bf16x8*)(Abase + (size_t)cs*16*CC + k);
#pragma unroll
    for (int ns=0;ns<2;++ns) bf[ns] = *(const bf16x8*)(Bbase + (size_t)ns*16*CC + k);
#pragma unroll
    for (int cs=0;cs<4;++cs)
#pragma unroll
      for (int ns=0;ns<2;++ns)
        acc[cs][ns] = __builtin_amdgcn_mfma_f32_16x16x32_bf16(af[cs], bf[ns], acc[cs][ns], 0,0,0);
  }
#pragma unroll
  for (int cs=0;cs<4;++cs){
#pragma unroll
    for (int r=0;r<4;++r){
      const int c = c0w + cs*16 + q*4 + r;
      const float bias = bv[c];
#pragma unroll
      for (int ns=0;ns<2;++ns){
        const int n = n0w + ns*16 + iq;
        Vbf[((size_t)b*CC + c)*NN + n] = (short)bf16_bits(acc[cs][ns][r] + bias);
      }
    }
  }
}

// ---- MFMA flash attention, barrier-free ----
// Grid 512: bid&7 = batch (XCD swizzle), bid>>3 = i-tile (64 rows).
// Each wave: computes full S^T (all j) for the i-tile, exp in-reg, and PV for its
// own 128 channels. C/D layout of S^T == B-operand layout of 16x16x16 MFMA, so
// P goes register->register into PV. No LDS, no barriers in the main loop.
__global__ __launch_bounds__(256, 2) void attn_mfma_kernel(
    const short* __restrict__ Qbf, const short* __restrict__ Kbf,
    const short* __restrict__ Vbf, const float* __restrict__ x,
    const float* __restrict__ gamma, float* __restrict__ out){
  const int tid  = threadIdx.x;
  const int lane = tid & 63;
  const int w    = tid >> 6;
  const int iq   = lane & 15;
  const int q    = lane >> 4;
  const int bid  = blockIdx.x;
  const int b    = bid & 7;
  const int i0   = (bid >> 3) * MQ;
  const int c0   = w * 128;

  // Q B-frags (persistent, 32 VGPR)
  bf16x8 qb[4][2];
#pragma unroll
  for (int s=0;s<4;++s){
    const short* qp = Qbf + ((size_t)b*NN + i0 + s*16 + iq)*CQ + q*8;
    qb[s][0] = *(const bf16x8*)qp;
    qb[s][1] = *(const bf16x8*)(qp + 32);
  }

  f32x4 acc[8][4];   // [c-sub][i-sub], 128 VGPR
#pragma unroll
  for (int cs=0;cs<8;++cs)
#pragma unroll
    for (int s=0;s<4;++s) acc[cs][s] = (f32x4){0.f,0.f,0.f,0.f};
  float lpart[4] = {0.f,0.f,0.f,0.f};

  const short* Kln = Kbf + ((size_t)b*NN + iq)*CQ + q*8;        // + j*CQ  (A: m=j-row iq, k=o)
  const short* Vln = Vbf + ((size_t)b*CC + c0 + iq)*NN + q*4;   // + cs*16*NN + j  (A: m=c, k=j)

  for (int jt=0; jt<NN/64; ++jt){
#pragma unroll
    for (int js=0; js<4; ++js){
      const int jb = jt*64 + js*16;
      // ---- S^T (16 j x 64 i): A = K rows, B = Q ----
      const short* kp = Kln + (size_t)jb*CQ;
      const bf16x8 ka0 = *(const bf16x8*)kp;
      const bf16x8 ka1 = *(const bf16x8*)(kp + 32);
      f32x4 sf[4];
#pragma unroll
      for (int s=0;s<4;++s){
        sf[s] = __builtin_amdgcn_mfma_f32_16x16x32_bf16(ka0, qb[s][0], (f32x4){0.f,0.f,0.f,0.f}, 0,0,0);
        sf[s] = __builtin_amdgcn_mfma_f32_16x16x32_bf16(ka1, qb[s][1], sf[s], 0,0,0);
      }
      // ---- exp + pack: C/D regs (j=q*4+r, i=iq) ARE the B-frag (k=q*4+e, n=iq) ----
      bf16x4 pb[4];
#pragma unroll
      for (int s=0;s<4;++s){
        const float p0 = __expf(sf[s][0]);
        const float p1 = __expf(sf[s][1]);
        const float p2 = __expf(sf[s][2]);
        const float p3 = __expf(sf[s][3]);
        lpart[s] += (p0+p1) + (p2+p3);
        union { unsigned u[2]; bf16x4 v; } pu;
        pu.u[0] = pack2bf(p0, p1);
        pu.u[1] = pack2bf(p2, p3);
        pb[s] = pu.v;
      }
      // ---- PV: A = V (m=c, k=j, 8B frags), B = pb, K=16 ----
#pragma unroll
      for (int cs=0;cs<8;++cs){
        const bf16x4 va = *(const bf16x4*)(Vln + (size_t)cs*16*NN + jb);
#pragma unroll
        for (int s=0;s<4;++s)
          acc[cs][s] = __builtin_amdgcn_mfma_f32_16x16x16bf16_1k(va, pb[s], acc[cs][s], 0,0,0);
      }
    }
  }

  // ---- l: wave-local (each wave computed all j). Reduce across quads. ----
  float linv[4];
#pragma unroll
  for (int s=0;s<4;++s){
    float l = lpart[s];
    l += __shfl_xor(l, 16, 64);
    l += __shfl_xor(l, 32, 64);
    linv[s] = 1.0f / l;
  }

  // ---- epilogue: out[c][i] = gamma * O^T[c][i]/l[i] + x[c][i] ----
  const float gam = gamma[0];
#pragma unroll
  for (int cs=0;cs<8;++cs){
#pragma unroll
    for (int s=0;s<4;++s){
      const int cb = c0 + cs*16 + q*4;
      const int i  = i0 + s*16 + iq;
#pragma unroll
      for (int r=0;r<4;++r){
        const size_t idx = ((size_t)b*CC + cb + r)*NN + i;
        out[idx] = fmaf(gam, acc[cs][s][r]*linv[s], x[idx]);
      }
    }
  }
}

extern "C" void kernel_launch(void* const* d_in, const int* in_sizes, int n_in,
                              void* d_out, int out_size, void* d_ws, size_t ws_size,
                              hipStream_t stream){
  const float* x     = (const float*)d_in[0];
  const float* Wq    = (const float*)d_in[1];
  const float* bq    = (const float*)d_in[2];
  const float* Wk    = (const float*)d_in[3];
  const float* bk    = (const float*)d_in[4];
  const float* Wv    = (const float*)d_in[5];
  const float* bv    = (const float*)d_in[6];
  const float* gamma = (const float*)d_in[7];
  float* out = (float*)d_out;

  // workspace: xT bf16 [8][4096][512] 33.6MB; Qbf/Kbf bf16 [8][4096][64] 4.2MB each;
  // Vbf bf16 [8][512][4096] 33.6MB; Wqkbf [128][512] 128KB; Wvbf [512][512] 512KB. ~76 MB
  short* xTbf = (short*)d_ws;
  short* Qbf  = xTbf + (size_t)BB*NN*CC;
  short* Kbf  = Qbf  + (size_t)BB*NN*CQ;
  short* Vbf  = Kbf  + (size_t)BB*NN*CQ;
  short* Wqkbf= Vbf  + (size_t)BB*CC*NN;
  short* Wvbf = Wqkbf + (size_t)2*CQ*CC;

  cvt_w_kernel<<<dim3(CC*CC/256), 256, 0, stream>>>(Wq, Wk, Wv, Wqkbf, Wvbf);
  cvt_x_kernel<<<dim3(NN/64, CC/64, BB), 256, 0, stream>>>(x, xTbf);
  proj_qk_mfma<<<dim3(NN/128, 1, BB), 256, 0, stream>>>(xTbf, Wqkbf, bq, bk, Qbf, Kbf);
  proj_v_mfma<<<dim3(NN/64, CC/128, BB), 256, 0, stream>>>(xTbf, Wvbf, bv, Vbf);
  attn_mfma_kernel<<<dim3(BB*NN/MQ), 256, 0, stream>>>(Qbf, Kbf, Vbf, x, gamma, out);
}